// Round 1
// baseline (1746.699 us; speedup 1.0000x reference)
//
#include <hip/hip_runtime.h>
#include <math.h>

// ---------------------------------------------------------------------------
// QuantMlp: out = fq(h)@fq(W2)^T + b2,  h = gelu(fq(LN(x))@fq(W1)^T + b1)
// fq: per-tensor symmetric int8 fake-quant. Since q-values are small integers,
// they are EXACT in bf16 and bf16-MFMA fp32 accumulation of q*q' is exact
// (partial sums < 2^24). So all GEMMs run on bf16 MFMA with integer inputs,
// scales applied in the epilogue.
// ---------------------------------------------------------------------------

typedef __attribute__((ext_vector_type(4))) float  f4;
typedef __attribute__((ext_vector_type(8))) __bf16 bf16x8;
typedef __attribute__((ext_vector_type(4))) unsigned short us4;
typedef __attribute__((ext_vector_type(4))) unsigned int   u4;

__device__ __forceinline__ unsigned short f2bf_rn(float f) {
    unsigned u = __float_as_uint(f);
    u += 0x7FFFu + ((u >> 16) & 1u);          // round-to-nearest-even
    return (unsigned short)(u >> 16);
}
__device__ __forceinline__ float bf2f(unsigned short b) {
    return __uint_as_float(((unsigned)b) << 16);
}

// all-256-thread block -> single device atomicMax of a non-negative float
__device__ __forceinline__ void block_atomic_max(float v, unsigned* slot,
                                                 float* red, int tid) {
    int lane = tid & 63, wv = tid >> 6;
    #pragma unroll
    for (int m = 32; m; m >>= 1) v = fmaxf(v, __shfl_xor(v, m));
    if (lane == 0) red[wv] = v;
    __syncthreads();
    if (tid == 0) {
        float r = fmaxf(fmaxf(red[0], red[1]), fmaxf(red[2], red[3]));
        atomicMax(slot, __float_as_uint(r));
    }
}

// async 16B global->LDS (wave-uniform base + lane*16 by construction)
__device__ __forceinline__ void gll16(const void* g, void* l) {
    __builtin_amdgcn_global_load_lds(
        (const __attribute__((address_space(1))) void*)g,
        (__attribute__((address_space(3))) void*)l, 16, 0, 0);
}

// ---------------------------------------------------------------------------
// LayerNorm helpers: one wave per row of 768 (12 floats/lane as 3x float4)
// ---------------------------------------------------------------------------
__device__ __forceinline__ void ln_row(const f4* xr, int lane, f4 v[3],
                                       float& mu, float& rs) {
    float s = 0.f;
    #pragma unroll
    for (int c = 0; c < 3; c++) {
        v[c] = xr[lane + 64 * c];
        s += v[c][0] + v[c][1] + v[c][2] + v[c][3];
    }
    #pragma unroll
    for (int m = 1; m < 64; m <<= 1) s += __shfl_xor(s, m);
    mu = s * (1.0f / 768.0f);
    float q = 0.f;
    #pragma unroll
    for (int c = 0; c < 3; c++) {
        #pragma unroll
        for (int k = 0; k < 4; k++) { float d = v[c][k] - mu; q += d * d; }
    }
    #pragma unroll
    for (int m = 1; m < 64; m <<= 1) q += __shfl_xor(q, m);
    rs = rsqrtf(q * (1.0f / 768.0f) + 1e-5f);
}

__global__ __launch_bounds__(256) void ln_absmax_kernel(
        const float* __restrict__ x, const float* __restrict__ gamma,
        const float* __restrict__ beta, unsigned* __restrict__ slot, long NR) {
    __shared__ float red[4];
    int tid = threadIdx.x, lane = tid & 63, wv = tid >> 6;
    const f4* g4 = (const f4*)gamma;
    const f4* b4 = (const f4*)beta;
    long rstep = (long)gridDim.x * 4;
    float wmax = 0.f;
    for (long row = (long)blockIdx.x * 4 + wv; row < NR; row += rstep) {
        const f4* xr = (const f4*)(x + row * 768);
        f4 v[3]; float mu, rs;
        ln_row(xr, lane, v, mu, rs);
        #pragma unroll
        for (int c = 0; c < 3; c++) {
            f4 g = g4[lane + 64 * c], b = b4[lane + 64 * c];
            #pragma unroll
            for (int k = 0; k < 4; k++) {
                float xn = (v[c][k] - mu) * rs * g[k] + b[k];
                wmax = fmaxf(wmax, fabsf(xn));
            }
        }
    }
    block_atomic_max(wmax, slot, red, tid);
}

__global__ __launch_bounds__(256) void ln_quant_kernel(
        const float* __restrict__ x, const float* __restrict__ gamma,
        const float* __restrict__ beta, unsigned short* __restrict__ qx,
        const unsigned* __restrict__ amax_bits, long NR) {
    int tid = threadIdx.x, lane = tid & 63, wv = tid >> 6;
    long row = (long)blockIdx.x * 4 + wv;
    if (row >= NR) return;
    float sx = fmaxf(__uint_as_float(*amax_bits) * (1.0f / 128.0f), 1e-12f);
    const f4* xr = (const f4*)(x + row * 768);
    const f4* g4 = (const f4*)gamma;
    const f4* b4 = (const f4*)beta;
    f4 v[3]; float mu, rs;
    ln_row(xr, lane, v, mu, rs);
    us4* qr = (us4*)(qx + row * 768);
    #pragma unroll
    for (int c = 0; c < 3; c++) {
        f4 g = g4[lane + 64 * c], b = b4[lane + 64 * c];
        us4 o;
        #pragma unroll
        for (int k = 0; k < 4; k++) {
            float xn = (v[c][k] - mu) * rs * g[k] + b[k];
            float q = fminf(fmaxf(rintf(xn / sx), -128.0f), 127.0f);
            o[k] = f2bf_rn(q);   // exact: small integer
        }
        qr[lane + 64 * c] = o;
    }
}

// ---------------------------------------------------------------------------
// Weight absmax + quantize (fp32 -> integer-valued bf16)
// ---------------------------------------------------------------------------
__global__ __launch_bounds__(256) void absmax_kernel(
        const float* __restrict__ w, long n4, unsigned* __restrict__ slot) {
    __shared__ float red[4];
    int tid = threadIdx.x;
    long stride = (long)gridDim.x * 256;
    float mx = 0.f;
    for (long i = (long)blockIdx.x * 256 + tid; i < n4; i += stride) {
        f4 v = ((const f4*)w)[i];
        mx = fmaxf(mx, fmaxf(fmaxf(fabsf(v[0]), fabsf(v[1])),
                             fmaxf(fabsf(v[2]), fabsf(v[3]))));
    }
    block_atomic_max(mx, slot, red, tid);
}

__global__ __launch_bounds__(256) void quant_w_kernel(
        const float* __restrict__ w, unsigned short* __restrict__ qw, long n4,
        const unsigned* __restrict__ amax_bits) {
    long i = (long)blockIdx.x * 256 + threadIdx.x;
    if (i >= n4) return;
    float s = fmaxf(__uint_as_float(*amax_bits) * (1.0f / 127.0f), 1e-12f);
    f4 v = ((const f4*)w)[i];
    us4 o;
    #pragma unroll
    for (int k = 0; k < 4; k++) {
        float q = fminf(fmaxf(rintf(v[k] / s), -127.0f), 127.0f);
        o[k] = f2bf_rn(q);
    }
    ((us4*)qw)[i] = o;
}

// h (bf16) -> q (integer-valued bf16), in place. 8 elements / thread.
__global__ __launch_bounds__(256) void quant_h_kernel(
        unsigned short* __restrict__ h, const unsigned* __restrict__ amax_bits,
        long n8) {
    long i = (long)blockIdx.x * 256 + threadIdx.x;
    if (i >= n8) return;
    float s = fmaxf(__uint_as_float(*amax_bits) * (1.0f / 128.0f), 1e-12f);
    u4 d = ((const u4*)h)[i];
    u4 o;
    #pragma unroll
    for (int k = 0; k < 4; k++) {
        float a = bf2f((unsigned short)(d[k] & 0xFFFFu));
        float b = bf2f((unsigned short)(d[k] >> 16));
        float qa = fminf(fmaxf(rintf(a / s), -128.0f), 127.0f);
        float qb = fminf(fmaxf(rintf(b / s), -128.0f), 127.0f);
        o[k] = (unsigned)f2bf_rn(qa) | ((unsigned)f2bf_rn(qb) << 16);
    }
    ((u4*)h)[i] = o;
}

// ---------------------------------------------------------------------------
// GEMM: C[M,N] = A[M,K] * B[N,K]^T, A/B integer-valued bf16, K-contiguous.
// 128x128 block tile, BK=64, 4 waves in 2x2, each wave 4x4 of 16x16x32 MFMA.
// LDS staged via global_load_lds(16B); XOR swizzle (chunk ^= row&7) breaks the
// 128B-stride bank conflict on ds_read_b128 (<=2-way: free per m136).
// EPI 0: h-epilogue (scale+bias, exact gelu, fp32 absmax, bf16 store)
// EPI 1: out-epilogue (scale+bias, fp32 store)
// ---------------------------------------------------------------------------
template <int EPI>
__global__ __launch_bounds__(256) void gemm_bt(
        const unsigned short* __restrict__ A, const unsigned short* __restrict__ B,
        int K, const unsigned* __restrict__ amaxA_bits,
        const unsigned* __restrict__ amaxB_bits, const float* __restrict__ bias,
        void* __restrict__ Cout, int ldc, unsigned* __restrict__ amax_out) {
    __shared__ __align__(16) char lds[32768];
    __shared__ float red[4];
    char* As = lds;
    char* Bs = lds + 16384;
    int tid = threadIdx.x, lane = tid & 63, wv = tid >> 6;
    int wr = (wv >> 1) * 64, wc = (wv & 1) * 64;
    long rowBase = (long)blockIdx.y * 128;
    long colBase = (long)blockIdx.x * 128;
    f4 acc[4][4] = {};

    for (int kt = 0; kt < K; kt += 64) {
        __syncthreads();
        #pragma unroll
        for (int r = 0; r < 4; r++) {
            int sc = r * 256 + tid;          // LDS 16B slot 0..1023
            int srow = sc >> 3, skc = sc & 7;
            int gk = kt + ((skc ^ (srow & 7)) << 3);
            gll16(A + (rowBase + srow) * (long)K + gk, As + sc * 16);
            gll16(B + (colBase + srow) * (long)K + gk, Bs + sc * 16);
        }
        __syncthreads();
        #pragma unroll
        for (int step = 0; step < 2; step++) {
            bf16x8 af[4], bfr[4];
            int j = step * 4 + (lane >> 4);
            int sw = (j ^ (lane & 7)) * 16;
            #pragma unroll
            for (int t = 0; t < 4; t++) {
                af[t]  = *(const bf16x8*)(As + (wr + t * 16 + (lane & 15)) * 128 + sw);
                bfr[t] = *(const bf16x8*)(Bs + (wc + t * 16 + (lane & 15)) * 128 + sw);
            }
            #pragma unroll
            for (int mt = 0; mt < 4; mt++)
                #pragma unroll
                for (int nt = 0; nt < 4; nt++)
                    acc[mt][nt] = __builtin_amdgcn_mfma_f32_16x16x32_bf16(
                        af[mt], bfr[nt], acc[mt][nt], 0, 0, 0);
        }
    }

    float sA = fmaxf(__uint_as_float(*amaxA_bits) * (1.0f / 128.0f), 1e-12f);
    float sB = fmaxf(__uint_as_float(*amaxB_bits) * (1.0f / 127.0f), 1e-12f);
    float sAB = sA * sB;
    int cr = (lane >> 4) * 4;   // C row offset within 16  (row=(lane>>4)*4+reg)
    int cc = lane & 15;         // C col within 16         (col=lane&15)

    if (EPI == 0) {
        unsigned short* Hm = (unsigned short*)Cout;
        float mx = 0.f;
        #pragma unroll
        for (int nt = 0; nt < 4; nt++) {
            long col = colBase + wc + nt * 16 + cc;
            float bv = bias[col];
            #pragma unroll
            for (int mt = 0; mt < 4; mt++) {
                long row0 = rowBase + wr + mt * 16 + cr;
                #pragma unroll
                for (int r = 0; r < 4; r++) {
                    float v = acc[mt][nt][r] * sAB + bv;
                    float g = 0.5f * v * (1.0f + erff(v * 0.70710678118654752f));
                    mx = fmaxf(mx, fabsf(g));
                    Hm[(row0 + r) * (long)ldc + col] = f2bf_rn(g);
                }
            }
        }
        block_atomic_max(mx, amax_out, red, tid);
    } else {
        float* O = (float*)Cout;
        #pragma unroll
        for (int nt = 0; nt < 4; nt++) {
            long col = colBase + wc + nt * 16 + cc;
            float bv = bias[col];
            #pragma unroll
            for (int mt = 0; mt < 4; mt++) {
                long row0 = rowBase + wr + mt * 16 + cr;
                #pragma unroll
                for (int r = 0; r < 4; r++)
                    O[(row0 + r) * (long)ldc + col] = acc[mt][nt][r] * sAB + bv;
            }
        }
    }
}

// ---------------------------------------------------------------------------
extern "C" void kernel_launch(void* const* d_in, const int* in_sizes, int n_in,
                              void* d_out, int out_size, void* d_ws, size_t ws_size,
                              hipStream_t stream) {
    const float* x     = (const float*)d_in[0];
    const float* gamma = (const float*)d_in[1];
    const float* beta  = (const float*)d_in[2];
    const float* W1    = (const float*)d_in[3];
    const float* b1    = (const float*)d_in[4];
    const float* W2    = (const float*)d_in[5];
    const float* b2    = (const float*)d_in[6];
    float* out = (float*)d_out;

    const int  D  = in_sizes[1];          // 768
    const int  H  = in_sizes[4];          // 3072
    const long NR = (long)in_sizes[0] / D;  // 65536

    char* ws = (char*)d_ws;
    unsigned* amax = (unsigned*)ws;                 // [0]=x [1]=W1 [2]=W2 [3]=h
    unsigned short* qx  = (unsigned short*)(ws + 256);
    unsigned short* qw1 = qx  + (size_t)NR * D;
    unsigned short* qw2 = qw1 + (size_t)H * D;
    unsigned short* hq  = qw2 + (size_t)H * D;      // NR*H bf16

    hipMemsetAsync(amax, 0, 16, stream);

    long wn4 = (long)H * D / 4;
    absmax_kernel<<<1024, 256, 0, stream>>>(W1, wn4, amax + 1);
    absmax_kernel<<<1024, 256, 0, stream>>>(W2, wn4, amax + 2);
    ln_absmax_kernel<<<2048, 256, 0, stream>>>(x, gamma, beta, amax + 0, NR);

    quant_w_kernel<<<(unsigned)((wn4 + 255) / 256), 256, 0, stream>>>(W1, qw1, wn4, amax + 1);
    quant_w_kernel<<<(unsigned)((wn4 + 255) / 256), 256, 0, stream>>>(W2, qw2, wn4, amax + 2);
    ln_quant_kernel<<<(unsigned)(NR / 4), 256, 0, stream>>>(x, gamma, beta, qx, amax + 0, NR);

    dim3 g1(H / 128, (unsigned)(NR / 128));
    gemm_bt<0><<<g1, 256, 0, stream>>>(qx, qw1, D, amax + 0, amax + 1, b1,
                                       (void*)hq, H, amax + 3);

    long n8 = NR * (long)H / 8;
    quant_h_kernel<<<(unsigned)((n8 + 255) / 256), 256, 0, stream>>>(hq, amax + 3, n8);

    dim3 g2(D / 128, (unsigned)(NR / 128));
    gemm_bt<1><<<g2, 256, 0, stream>>>(hq, qw2, H, amax + 3, amax + 2, b2,
                                       (void*)out, D, nullptr);
}

// Round 2
// 1646.681 us; speedup vs baseline: 1.0607x; 1.0607x over previous
//
#include <hip/hip_runtime.h>
#include <math.h>

// ---------------------------------------------------------------------------
// QuantMlp: out = fq(h)@fq(W2)^T + b2,  h = gelu(fq(LN(x))@fq(W1)^T + b1)
// fq: per-tensor symmetric int8 fake-quant. q-values are small integers ->
// EXACT in bf16; bf16-MFMA fp32 accumulation of q*q' is exact (sums < 2^24).
// GEMMs run on bf16 MFMA with integer inputs, scales applied in epilogue.
//
// R1 -> R2: GEMM K-loop restructured to BK=32 double-buffered pipeline:
//   - ONE barrier per ktile; async gll16 prefetch issued BEFORE compute so
//     the vmcnt(0) drain at the next barrier comes after latency is hidden.
//   - staging addresses are loop-invariant pointers += 64 B/iter.
//   - XOR swizzle j ^= (row&3)^((row>>2)&3) for 64B row stride (<=2-way).
// ---------------------------------------------------------------------------

typedef __attribute__((ext_vector_type(4))) float  f4;
typedef __attribute__((ext_vector_type(8))) __bf16 bf16x8;
typedef __attribute__((ext_vector_type(4))) unsigned short us4;
typedef __attribute__((ext_vector_type(4))) unsigned int   u4;

__device__ __forceinline__ unsigned short f2bf_rn(float f) {
    unsigned u = __float_as_uint(f);
    u += 0x7FFFu + ((u >> 16) & 1u);          // round-to-nearest-even
    return (unsigned short)(u >> 16);
}
__device__ __forceinline__ float bf2f(unsigned short b) {
    return __uint_as_float(((unsigned)b) << 16);
}

// all-256-thread block -> single device atomicMax of a non-negative float
__device__ __forceinline__ void block_atomic_max(float v, unsigned* slot,
                                                 float* red, int tid) {
    int lane = tid & 63, wv = tid >> 6;
    #pragma unroll
    for (int m = 32; m; m >>= 1) v = fmaxf(v, __shfl_xor(v, m));
    if (lane == 0) red[wv] = v;
    __syncthreads();
    if (tid == 0) {
        float r = fmaxf(fmaxf(red[0], red[1]), fmaxf(red[2], red[3]));
        atomicMax(slot, __float_as_uint(r));
    }
}

// async 16B global->LDS (wave-uniform base + lane*16 by construction)
__device__ __forceinline__ void gll16(const void* g, void* l) {
    __builtin_amdgcn_global_load_lds(
        (const __attribute__((address_space(1))) void*)g,
        (__attribute__((address_space(3))) void*)l, 16, 0, 0);
}

// ---------------------------------------------------------------------------
// LayerNorm helpers: one wave per row of 768 (12 floats/lane as 3x float4)
// ---------------------------------------------------------------------------
__device__ __forceinline__ void ln_row(const f4* xr, int lane, f4 v[3],
                                       float& mu, float& rs) {
    float s = 0.f;
    #pragma unroll
    for (int c = 0; c < 3; c++) {
        v[c] = xr[lane + 64 * c];
        s += v[c][0] + v[c][1] + v[c][2] + v[c][3];
    }
    #pragma unroll
    for (int m = 1; m < 64; m <<= 1) s += __shfl_xor(s, m);
    mu = s * (1.0f / 768.0f);
    float q = 0.f;
    #pragma unroll
    for (int c = 0; c < 3; c++) {
        #pragma unroll
        for (int k = 0; k < 4; k++) { float d = v[c][k] - mu; q += d * d; }
    }
    #pragma unroll
    for (int m = 1; m < 64; m <<= 1) q += __shfl_xor(q, m);
    rs = rsqrtf(q * (1.0f / 768.0f) + 1e-5f);
}

__global__ __launch_bounds__(256) void ln_absmax_kernel(
        const float* __restrict__ x, const float* __restrict__ gamma,
        const float* __restrict__ beta, unsigned* __restrict__ slot, long NR) {
    __shared__ float red[4];
    int tid = threadIdx.x, lane = tid & 63, wv = tid >> 6;
    const f4* g4 = (const f4*)gamma;
    const f4* b4 = (const f4*)beta;
    long rstep = (long)gridDim.x * 4;
    float wmax = 0.f;
    for (long row = (long)blockIdx.x * 4 + wv; row < NR; row += rstep) {
        const f4* xr = (const f4*)(x + row * 768);
        f4 v[3]; float mu, rs;
        ln_row(xr, lane, v, mu, rs);
        #pragma unroll
        for (int c = 0; c < 3; c++) {
            f4 g = g4[lane + 64 * c], b = b4[lane + 64 * c];
            #pragma unroll
            for (int k = 0; k < 4; k++) {
                float xn = (v[c][k] - mu) * rs * g[k] + b[k];
                wmax = fmaxf(wmax, fabsf(xn));
            }
        }
    }
    block_atomic_max(wmax, slot, red, tid);
}

__global__ __launch_bounds__(256) void ln_quant_kernel(
        const float* __restrict__ x, const float* __restrict__ gamma,
        const float* __restrict__ beta, unsigned short* __restrict__ qx,
        const unsigned* __restrict__ amax_bits, long NR) {
    int tid = threadIdx.x, lane = tid & 63, wv = tid >> 6;
    long row = (long)blockIdx.x * 4 + wv;
    if (row >= NR) return;
    float sx = fmaxf(__uint_as_float(*amax_bits) * (1.0f / 128.0f), 1e-12f);
    const f4* xr = (const f4*)(x + row * 768);
    const f4* g4 = (const f4*)gamma;
    const f4* b4 = (const f4*)beta;
    f4 v[3]; float mu, rs;
    ln_row(xr, lane, v, mu, rs);
    us4* qr = (us4*)(qx + row * 768);
    #pragma unroll
    for (int c = 0; c < 3; c++) {
        f4 g = g4[lane + 64 * c], b = b4[lane + 64 * c];
        us4 o;
        #pragma unroll
        for (int k = 0; k < 4; k++) {
            float xn = (v[c][k] - mu) * rs * g[k] + b[k];
            float q = fminf(fmaxf(rintf(xn / sx), -128.0f), 127.0f);
            o[k] = f2bf_rn(q);   // exact: small integer
        }
        qr[lane + 64 * c] = o;
    }
}

// ---------------------------------------------------------------------------
// Weight absmax + quantize (fp32 -> integer-valued bf16)
// ---------------------------------------------------------------------------
__global__ __launch_bounds__(256) void absmax_kernel(
        const float* __restrict__ w, long n4, unsigned* __restrict__ slot) {
    __shared__ float red[4];
    int tid = threadIdx.x;
    long stride = (long)gridDim.x * 256;
    float mx = 0.f;
    for (long i = (long)blockIdx.x * 256 + tid; i < n4; i += stride) {
        f4 v = ((const f4*)w)[i];
        mx = fmaxf(mx, fmaxf(fmaxf(fabsf(v[0]), fabsf(v[1])),
                             fmaxf(fabsf(v[2]), fabsf(v[3]))));
    }
    block_atomic_max(mx, slot, red, tid);
}

__global__ __launch_bounds__(256) void quant_w_kernel(
        const float* __restrict__ w, unsigned short* __restrict__ qw, long n4,
        const unsigned* __restrict__ amax_bits) {
    long i = (long)blockIdx.x * 256 + threadIdx.x;
    if (i >= n4) return;
    float s = fmaxf(__uint_as_float(*amax_bits) * (1.0f / 127.0f), 1e-12f);
    f4 v = ((const f4*)w)[i];
    us4 o;
    #pragma unroll
    for (int k = 0; k < 4; k++) {
        float q = fminf(fmaxf(rintf(v[k] / s), -127.0f), 127.0f);
        o[k] = f2bf_rn(q);
    }
    ((us4*)qw)[i] = o;
}

// h (bf16) -> q (integer-valued bf16), in place. 8 elements / thread.
__global__ __launch_bounds__(256) void quant_h_kernel(
        unsigned short* __restrict__ h, const unsigned* __restrict__ amax_bits,
        long n8) {
    long i = (long)blockIdx.x * 256 + threadIdx.x;
    if (i >= n8) return;
    float s = fmaxf(__uint_as_float(*amax_bits) * (1.0f / 128.0f), 1e-12f);
    u4 d = ((const u4*)h)[i];
    u4 o;
    #pragma unroll
    for (int k = 0; k < 4; k++) {
        float a = bf2f((unsigned short)(d[k] & 0xFFFFu));
        float b = bf2f((unsigned short)(d[k] >> 16));
        float qa = fminf(fmaxf(rintf(a / s), -128.0f), 127.0f);
        float qb = fminf(fmaxf(rintf(b / s), -128.0f), 127.0f);
        o[k] = (unsigned)f2bf_rn(qa) | ((unsigned)f2bf_rn(qb) << 16);
    }
    ((u4*)h)[i] = o;
}

// ---------------------------------------------------------------------------
// GEMM: C[M,N] = A[M,K] * B[N,K]^T, A/B integer-valued bf16, K-contiguous.
// 128x128 block tile, BK=32 double-buffered, 4 waves 2x2, 4x4 of 16x16x32.
// Per ktile: 1 barrier; prefetch (4x gll16) issued before compute so the
// barrier's vmcnt(0) drain comes after ~400 cyc of ds_read+MFMA.
// LDS: 2 buffers x (A 8KB | B 8KB) = 32 KB.
// Row = 64 B = 4 chunks of 16 B; chunk swizzled by (row&3)^((row>>2)&3).
// EPI 0: h-epilogue (scale+bias, exact gelu, fp32 absmax, bf16 store)
// EPI 1: out-epilogue (scale+bias, fp32 store)
// ---------------------------------------------------------------------------
template <int EPI>
__global__ __launch_bounds__(256) void gemm_bt(
        const unsigned short* __restrict__ A, const unsigned short* __restrict__ B,
        int K, const unsigned* __restrict__ amaxA_bits,
        const unsigned* __restrict__ amaxB_bits, const float* __restrict__ bias,
        void* __restrict__ Cout, int ldc, unsigned* __restrict__ amax_out) {
    __shared__ __align__(16) char lds[32768];
    __shared__ float red[4];
    int tid = threadIdx.x, lane = tid & 63, wv = tid >> 6;
    int wr = (wv >> 1) * 64, wc = (wv & 1) * 64;
    long rowBase = (long)blockIdx.y * 128;
    long colBase = (long)blockIdx.x * 128;
    f4 acc[4][4] = {};

    // ---- loop-invariant staging setup: thread p-th slot sc = p*256+tid ----
    // A tile: 128 rows x 32 k x 2B = 8 KB = 512 slots of 16B; row=sc>>2, c=sc&3
    const char* gA[2]; const char* gB[2]; int ldsA[2], ldsB[2];
    #pragma unroll
    for (int p = 0; p < 2; p++) {
        int sc = p * 256 + tid;
        int row = sc >> 2, c = sc & 3;
        int m = (row & 3) ^ ((row >> 2) & 3);
        int j = c ^ m;                        // global k-chunk for this slot
        gA[p] = (const char*)(A + (rowBase + row) * (long)K) + j * 16;
        gB[p] = (const char*)(B + (colBase + row) * (long)K) + j * 16;
        ldsA[p] = sc * 16;                    // within A region of a buffer
        ldsB[p] = 8192 + sc * 16;             // B region
    }

    // prologue: stage ktile 0 into buffer 0
    #pragma unroll
    for (int p = 0; p < 2; p++) {
        gll16(gA[p], lds + ldsA[p]);
        gll16(gB[p], lds + ldsB[p]);
    }
    gA[0] += 64; gA[1] += 64; gB[0] += 64; gB[1] += 64;

    int cur = 0;
    const int nkt = K >> 5;
    for (int it = 1; it < nkt; it++) {
        __syncthreads();                       // drains buf[cur] staging
        // prefetch next ktile into buf[cur^1]
        char* nb = lds + (cur ^ 1) * 16384;
        #pragma unroll
        for (int p = 0; p < 2; p++) {
            gll16(gA[p], nb + ldsA[p]);
            gll16(gB[p], nb + ldsB[p]);
        }
        gA[0] += 64; gA[1] += 64; gB[0] += 64; gB[1] += 64;
        // compute from buf[cur]
        {
            const char* As = lds + cur * 16384;
            const char* Bs = As + 8192;
            int c = lane >> 4;                 // k-chunk this lane reads
            int rl = lane & 15;
            int mz = (rl & 3) ^ ((rl >> 2) & 3);
            int sw = (c ^ mz) * 16;
            bf16x8 af[4], bfr[4];
            #pragma unroll
            for (int t = 0; t < 4; t++) {
                af[t]  = *(const bf16x8*)(As + (wr + t * 16 + rl) * 64 + sw);
                bfr[t] = *(const bf16x8*)(Bs + (wc + t * 16 + rl) * 64 + sw);
            }
            #pragma unroll
            for (int mt = 0; mt < 4; mt++)
                #pragma unroll
                for (int nt = 0; nt < 4; nt++)
                    acc[mt][nt] = __builtin_amdgcn_mfma_f32_16x16x32_bf16(
                        af[mt], bfr[nt], acc[mt][nt], 0, 0, 0);
        }
        cur ^= 1;
    }
    // last ktile
    __syncthreads();
    {
        const char* As = lds + cur * 16384;
        const char* Bs = As + 8192;
        int c = lane >> 4;
        int rl = lane & 15;
        int mz = (rl & 3) ^ ((rl >> 2) & 3);
        int sw = (c ^ mz) * 16;
        bf16x8 af[4], bfr[4];
        #pragma unroll
        for (int t = 0; t < 4; t++) {
            af[t]  = *(const bf16x8*)(As + (wr + t * 16 + rl) * 64 + sw);
            bfr[t] = *(const bf16x8*)(Bs + (wc + t * 16 + rl) * 64 + sw);
        }
        #pragma unroll
        for (int mt = 0; mt < 4; mt++)
            #pragma unroll
            for (int nt = 0; nt < 4; nt++)
                acc[mt][nt] = __builtin_amdgcn_mfma_f32_16x16x32_bf16(
                    af[mt], bfr[nt], acc[mt][nt], 0, 0, 0);
    }

    float sA = fmaxf(__uint_as_float(*amaxA_bits) * (1.0f / 128.0f), 1e-12f);
    float sB = fmaxf(__uint_as_float(*amaxB_bits) * (1.0f / 127.0f), 1e-12f);
    float sAB = sA * sB;
    int cr = (lane >> 4) * 4;   // C row offset within 16  (row=(lane>>4)*4+reg)
    int cc = lane & 15;         // C col within 16         (col=lane&15)

    if (EPI == 0) {
        unsigned short* Hm = (unsigned short*)Cout;
        float mx = 0.f;
        #pragma unroll
        for (int nt = 0; nt < 4; nt++) {
            long col = colBase + wc + nt * 16 + cc;
            float bv = bias[col];
            #pragma unroll
            for (int mt = 0; mt < 4; mt++) {
                long row0 = rowBase + wr + mt * 16 + cr;
                #pragma unroll
                for (int r = 0; r < 4; r++) {
                    float v = acc[mt][nt][r] * sAB + bv;
                    float g = 0.5f * v * (1.0f + erff(v * 0.70710678118654752f));
                    mx = fmaxf(mx, fabsf(g));
                    Hm[(row0 + r) * (long)ldc + col] = f2bf_rn(g);
                }
            }
        }
        block_atomic_max(mx, amax_out, red, tid);
    } else {
        float* O = (float*)Cout;
        #pragma unroll
        for (int nt = 0; nt < 4; nt++) {
            long col = colBase + wc + nt * 16 + cc;
            float bv = bias[col];
            #pragma unroll
            for (int mt = 0; mt < 4; mt++) {
                long row0 = rowBase + wr + mt * 16 + cr;
                #pragma unroll
                for (int r = 0; r < 4; r++)
                    O[(row0 + r) * (long)ldc + col] = acc[mt][nt][r] * sAB + bv;
            }
        }
    }
}

// ---------------------------------------------------------------------------
extern "C" void kernel_launch(void* const* d_in, const int* in_sizes, int n_in,
                              void* d_out, int out_size, void* d_ws, size_t ws_size,
                              hipStream_t stream) {
    const float* x     = (const float*)d_in[0];
    const float* gamma = (const float*)d_in[1];
    const float* beta  = (const float*)d_in[2];
    const float* W1    = (const float*)d_in[3];
    const float* b1    = (const float*)d_in[4];
    const float* W2    = (const float*)d_in[5];
    const float* b2    = (const float*)d_in[6];
    float* out = (float*)d_out;

    const int  D  = in_sizes[1];          // 768
    const int  H  = in_sizes[4];          // 3072
    const long NR = (long)in_sizes[0] / D;  // 65536

    char* ws = (char*)d_ws;
    unsigned* amax = (unsigned*)ws;                 // [0]=x [1]=W1 [2]=W2 [3]=h
    unsigned short* qx  = (unsigned short*)(ws + 256);
    unsigned short* qw1 = qx  + (size_t)NR * D;
    unsigned short* qw2 = qw1 + (size_t)H * D;
    unsigned short* hq  = qw2 + (size_t)H * D;      // NR*H bf16

    hipMemsetAsync(amax, 0, 16, stream);

    long wn4 = (long)H * D / 4;
    absmax_kernel<<<1024, 256, 0, stream>>>(W1, wn4, amax + 1);
    absmax_kernel<<<1024, 256, 0, stream>>>(W2, wn4, amax + 2);
    ln_absmax_kernel<<<2048, 256, 0, stream>>>(x, gamma, beta, amax + 0, NR);

    quant_w_kernel<<<(unsigned)((wn4 + 255) / 256), 256, 0, stream>>>(W1, qw1, wn4, amax + 1);
    quant_w_kernel<<<(unsigned)((wn4 + 255) / 256), 256, 0, stream>>>(W2, qw2, wn4, amax + 2);
    ln_quant_kernel<<<(unsigned)(NR / 4), 256, 0, stream>>>(x, gamma, beta, qx, amax + 0, NR);

    dim3 g1(H / 128, (unsigned)(NR / 128));
    gemm_bt<0><<<g1, 256, 0, stream>>>(qx, qw1, D, amax + 0, amax + 1, b1,
                                       (void*)hq, H, amax + 3);

    long n8 = NR * (long)H / 8;
    quant_h_kernel<<<(unsigned)((n8 + 255) / 256), 256, 0, stream>>>(hq, amax + 3, n8);

    dim3 g2(D / 128, (unsigned)(NR / 128));
    gemm_bt<1><<<g2, 256, 0, stream>>>(hq, qw2, H, amax + 3, amax + 2, b2,
                                       (void*)out, D, nullptr);
}